// Round 5
// baseline (901.247 us; speedup 1.0000x reference)
//
#include <hip/hip_runtime.h>
#include <hip/hip_bf16.h>

#define NTOK 49
#define DIM  256
#define NH   8
#define DH   32
#define NB   2048

// ---------- MFMA fragment types ----------
typedef __attribute__((ext_vector_type(8))) short bf16x8;
typedef __attribute__((ext_vector_type(4))) float f32x4;

// ---------- bf16 split helpers (native RNE cvt; split exact regardless of mode) ----------
__device__ __forceinline__ unsigned short f2bf(float f) {
  union { __hip_bfloat16 h; unsigned short u; } cv;
  cv.h = __float2bfloat16(f);
  return cv.u;
}
__device__ __forceinline__ float bf2f(unsigned short h) {
  return __uint_as_float(((unsigned int)h) << 16);
}

// ---------- dtype-polymorphic load/store ----------
__device__ __forceinline__ float ldf(const float* p, size_t i) { return p[i]; }
__device__ __forceinline__ float ldf(const __hip_bfloat16* p, size_t i) { return __bfloat162float(p[i]); }
__device__ __forceinline__ void stf(float* p, size_t i, float v) { p[i] = v; }
__device__ __forceinline__ void stf(__hip_bfloat16* p, size_t i, float v) { p[i] = __float2bfloat16(v); }

// ---------- dtype detector ----------
__global__ void dtype_detect_kernel(const unsigned int* __restrict__ x, int* flag) {
  if (blockIdx.x == 0 && threadIdx.x == 0) {
    int hits = 0;
    for (int i = 0; i < 64; ++i) {
      unsigned int lo = x[i] & 0xFFFFu;
      unsigned int e = (lo >> 7) & 0xFFu;
      if (e >= 110u && e <= 140u) hits++;
    }
    *flag = (hits >= 32) ? 1 : 0;   // 1 = bf16, 0 = fp32
  }
}

// ---------- workspace layout (ushorts, after 16-byte flag slot) ----------
#define OFF_QH 0
#define OFF_QL 196608
#define OFF_PH 393216
#define OFF_PL 458752
// bias table (f32, NH*2401) lives at byte offset 16 + 1048576 when ws allows

// ---------- prep: split weights into bf16 hi/lo; optional rpb-gather table ----------
template <typename T>
__global__ void prep_w_kernel(const T* __restrict__ qkv_w, const T* __restrict__ proj_w,
                              const T* __restrict__ rpb_table, const int* __restrict__ rel_index,
                              unsigned short* __restrict__ wsb, float* __restrict__ btbl,
                              int make_bt, const int* __restrict__ flag, int want) {
  if (*flag != want) return;
  int idx = blockIdx.x * blockDim.x + threadIdx.x;
  int stride = gridDim.x * blockDim.x;
  for (int i = idx; i < 768 * 256; i += stride) {
    float v = ldf(qkv_w, (size_t)i);
    unsigned short hb = f2bf(v);
    wsb[OFF_QH + i] = hb;
    wsb[OFF_QL + i] = f2bf(v - bf2f(hb));
  }
  for (int i = idx; i < 256 * 256; i += stride) {
    float v = ldf(proj_w, (size_t)i);
    unsigned short hb = f2bf(v);
    wsb[OFF_PH + i] = hb;
    wsb[OFF_PL + i] = f2bf(v - bf2f(hb));
  }
  if (make_bt) {
    for (int i = idx; i < NH * NTOK * NTOK; i += stride) {
      int h = i / (NTOK * NTOK), e = i - h * (NTOK * NTOK);
      btbl[i] = ldf(rpb_table, (size_t)rel_index[e] * NH + h);
    }
  }
}

// ---------- fully-MFMA fused QKV + window attention (2 heads / block) ----------
// Block = (window b, head-pair). 256 threads / 4 waves; wave pair (2hh,2hh+1) owns head hh.
// Phase 1: QKV GEMM  M=64(pad49) N=192(2 heads x 96) K=256, BK=64 shared x-staging;
//          B-frags (pre-split hi/lo) read directly from global/L2.  acc[4][3]=48 VGPR.
// Per head hh: pair-parallel epilogue -> QK^T (wave=16 rows x 64 cols, K=32) with
//          IN-REGISTER softmax (shfl_xor over 16-lane groups) -> P bf16 hi/lo to LDS -> PV.
// LDS 29696B: q/k hi/lo [64][40]us (20480) | V^T hi/lo [32][72]us (9216);
//          P hi/lo [64][72]us (18432) aliases q/k after post-QK^T barrier.
// -> 4 blocks/CU (launch_bounds(256,4), LDS 4x29696=116KB).
template <typename T>
__global__ __launch_bounds__(256, 4)
void win_attn_mfma_kernel(const T* __restrict__ x, const T* __restrict__ maskp,
                          const T* __restrict__ qkv_b,
                          const T* __restrict__ rpb_table, const int* __restrict__ rel_index,
                          const unsigned short* __restrict__ wsb,
                          const float* __restrict__ btbl, int has_bt,
                          T* __restrict__ out, const int* __restrict__ flag, int want)
{
  if (*flag != want) return;
  constexpr int NS = (sizeof(T) == 4) ? 2 : 1;
  __shared__ __align__(16) char smem[29696];

  // staging views (dead after phase 1)
  unsigned short* xh = (unsigned short*)smem;           // [64][72]
  unsigned short* xl = xh + 64 * 72;                    // (NS==2), ends @18432B
  // attention views
  unsigned short* qh_ = (unsigned short*)smem;          // [64][40] q hi (pre-scaled)
  unsigned short* ql_ = qh_ + 64 * 40;
  unsigned short* kh_ = ql_ + 64 * 40;
  unsigned short* kl_ = kh_ + 64 * 40;                  // ends @20480B
  unsigned short* vth = kl_ + 64 * 40;                  // [32][72] V^T hi (row=d, col=token)
  unsigned short* vtl = vth + 32 * 72;                  // ends @29696B
  unsigned short* ph_ = (unsigned short*)smem;          // [64][72] P hi (aliases q/k)
  unsigned short* pl_ = ph_ + 64 * 72;                  // ends @18432B

  const int b = blockIdx.x;
  const int hbase = blockIdx.y * 2;
  const int tid = threadIdx.x;
  const int lane = tid & 63, wid = tid >> 6;
  const int l15 = lane & 15, l4 = lane >> 4;
  const int myh = hbase + (wid >> 1);                   // this wave's head
  const int ncol0 = (wid & 1) * 48;                     // col-slice within head's 96
  const float SCALE = 0.17677669529663687f;             // 32^-0.5
  const size_t xbase = (size_t)b * NTOK * DIM;
  const unsigned short* qwh = wsb + OFF_QH;

  // B row bases (hi array; lo at +OFF_QL)
  size_t brow[3];
#pragma unroll
  for (int ni = 0; ni < 3; ++ni) {
    int j = ncol0 + ni * 16 + l15;
    brow[ni] = (size_t)((j >> 5) * DIM + myh * DH + (j & 31)) * DIM;
  }

  // zero V^T pad tokens j=49..63 ONCE (region disjoint from staging; epilogue writes j<49)
  for (int i = tid; i < 32 * 15; i += 256) {
    int d = i / 15, j2 = 49 + i % 15;
    vth[d * 72 + j2] = 0;
    vtl[d * 72 + j2] = 0;
  }

  // ================= Phase 1: QKV GEMM =================
  f32x4 acc[4][3];
#pragma unroll
  for (int mi = 0; mi < 4; ++mi)
#pragma unroll
    for (int ni = 0; ni < 3; ++ni) acc[mi][ni] = (f32x4){0.f, 0.f, 0.f, 0.f};

  for (int kt = 0; kt < DIM; kt += 64) {
    if constexpr (NS == 2) {
      const float* xf = reinterpret_cast<const float*>(x);
      for (int i = tid; i < NTOK * 16; i += 256) {
        int n = i >> 4, k4 = (i & 15) * 4;
        const float4 v = *(const float4*)(xf + xbase + n * DIM + kt + k4);
        ushort4 hh, ll;
        hh.x = f2bf(v.x); ll.x = f2bf(v.x - bf2f(hh.x));
        hh.y = f2bf(v.y); ll.y = f2bf(v.y - bf2f(hh.y));
        hh.z = f2bf(v.z); ll.z = f2bf(v.z - bf2f(hh.z));
        hh.w = f2bf(v.w); ll.w = f2bf(v.w - bf2f(hh.w));
        *(ushort4*)(xh + n * 72 + k4) = hh;
        *(ushort4*)(xl + n * 72 + k4) = ll;
      }
    } else {
      const unsigned short* xu = reinterpret_cast<const unsigned short*>(x);
      for (int i = tid; i < NTOK * 8; i += 256) {
        int n = i >> 3, k8 = (i & 7) * 8;
        *(int4*)(xh + n * 72 + k8) = *(const int4*)(xu + xbase + n * DIM + kt + k8);
      }
    }
    __syncthreads();

#pragma unroll
    for (int ks = 0; ks < 2; ++ks) {
      const int ka = ks * 32 + l4 * 8;
      bf16x8 Ah[4], Al[4];
#pragma unroll
      for (int mi = 0; mi < 4; ++mi) {
        int off = (mi * 16 + l15) * 72 + ka;
        Ah[mi] = *(const bf16x8*)(xh + off);
        if constexpr (NS == 2) Al[mi] = *(const bf16x8*)(xl + off);
      }
#pragma unroll
      for (int ni = 0; ni < 3; ++ni) {
        const unsigned short* bp = qwh + brow[ni] + kt + ka;
        bf16x8 Bh = *(const bf16x8*)bp;
#pragma unroll
        for (int mi = 0; mi < 4; ++mi)
          acc[mi][ni] = __builtin_amdgcn_mfma_f32_16x16x32_bf16(Ah[mi], Bh, acc[mi][ni], 0, 0, 0);
        if constexpr (NS == 2) {
          bf16x8 Bl = *(const bf16x8*)(bp + OFF_QL);
#pragma unroll
          for (int mi = 0; mi < 4; ++mi) {
            acc[mi][ni] = __builtin_amdgcn_mfma_f32_16x16x32_bf16(Ah[mi], Bl, acc[mi][ni], 0, 0, 0);
            acc[mi][ni] = __builtin_amdgcn_mfma_f32_16x16x32_bf16(Al[mi], Bh, acc[mi][ni], 0, 0, 0);
          }
        }
      }
    }
    __syncthreads();   // staging reads done before restage / scratch aliasing
  }

  // ================= per-head attention loop (2 heads) =================
  const size_t mbase = (size_t)(b & 63) * (NTOK * NTOK);
  for (int hh = 0; hh < 2; ++hh) {
    const int h = hbase + hh;

    // ---- epilogue: wave pair (2hh, 2hh+1) writes q/k/v for head hh ----
    if ((wid >> 1) == hh) {
#pragma unroll
      for (int mi = 0; mi < 4; ++mi) {
        int rbase = mi * 16 + l4 * 4;
#pragma unroll
        for (int ni = 0; ni < 3; ++ni) {
          int j = ncol0 + ni * 16 + l15;
          int c = j >> 5, d = j & 31;
          float bias = ldf(qkv_b, (size_t)(c * DIM + h * DH + d));
#pragma unroll
          for (int r = 0; r < 4; ++r) {
            int row = rbase + r;
            if (row < NTOK) {
              float val = acc[mi][ni][r] + bias;
              if (c == 0) {
                val *= SCALE;
                unsigned short hb = f2bf(val);
                qh_[row * 40 + d] = hb;
                ql_[row * 40 + d] = f2bf(val - bf2f(hb));
              } else if (c == 1) {
                unsigned short hb = f2bf(val);
                kh_[row * 40 + d] = hb;
                kl_[row * 40 + d] = f2bf(val - bf2f(hb));
              } else {
                unsigned short hb = f2bf(val);
                vth[d * 72 + row] = hb;
                vtl[d * 72 + row] = f2bf(val - bf2f(hb));
              }
            }
          }
        }
      }
    }
    __syncthreads();

    // ---- QK^T: wave owns rows wid*16..+15, cols 0..63 (K=32) ----
    f32x4 sacc[4];
#pragma unroll
    for (int nj = 0; nj < 4; ++nj) sacc[nj] = (f32x4){0.f, 0.f, 0.f, 0.f};
    {
      const int qoff = (wid * 16 + l15) * 40 + l4 * 8;
      bf16x8 Aqh = *(const bf16x8*)(qh_ + qoff);
      bf16x8 Aql = *(const bf16x8*)(ql_ + qoff);
#pragma unroll
      for (int nj = 0; nj < 4; ++nj) {
        const int koff2 = (nj * 16 + l15) * 40 + l4 * 8;
        bf16x8 Bkh = *(const bf16x8*)(kh_ + koff2);
        bf16x8 Bkl = *(const bf16x8*)(kl_ + koff2);
        sacc[nj] = __builtin_amdgcn_mfma_f32_16x16x32_bf16(Aqh, Bkh, sacc[nj], 0, 0, 0);
        sacc[nj] = __builtin_amdgcn_mfma_f32_16x16x32_bf16(Aqh, Bkl, sacc[nj], 0, 0, 0);
        sacc[nj] = __builtin_amdgcn_mfma_f32_16x16x32_bf16(Aql, Bkh, sacc[nj], 0, 0, 0);
      }
    }

    // ---- bias + mask + IN-REGISTER softmax ----
    // lane holds rows {wid*16+l4*4+r} x cols {nj*16+l15}; row-reduce = fold nj + shfl_xor(1,2,4,8)
    float sv[4][4];
#pragma unroll
    for (int nj = 0; nj < 4; ++nj) {
      const int col = nj * 16 + l15;
#pragma unroll
      for (int r = 0; r < 4; ++r) {
        const int row = wid * 16 + l4 * 4 + r;
        float s = -3.4e38f;
        if (col < NTOK && row < NTOK) {
          const int e = row * NTOK + col;
          float bias = has_bt ? btbl[h * (NTOK * NTOK) + e]
                              : ldf(rpb_table, (size_t)rel_index[e] * NH + h);
          s = sacc[nj][r] + bias + ldf(maskp, mbase + e);
        }
        sv[nj][r] = s;
      }
    }
    float mx[4], sums[4], inv[4];
#pragma unroll
    for (int r = 0; r < 4; ++r)
      mx[r] = fmaxf(fmaxf(sv[0][r], sv[1][r]), fmaxf(sv[2][r], sv[3][r]));
#pragma unroll
    for (int m = 1; m <= 8; m <<= 1)
#pragma unroll
      for (int r = 0; r < 4; ++r)
        mx[r] = fmaxf(mx[r], __shfl_xor(mx[r], m));
#pragma unroll
    for (int r = 0; r < 4; ++r) sums[r] = 0.f;
#pragma unroll
    for (int nj = 0; nj < 4; ++nj) {
      const int col = nj * 16 + l15;
#pragma unroll
      for (int r = 0; r < 4; ++r) {
        float ev = (col < NTOK) ? __expf(sv[nj][r] - mx[r]) : 0.f;
        sv[nj][r] = ev;
        sums[r] += ev;
      }
    }
#pragma unroll
    for (int m = 1; m <= 8; m <<= 1)
#pragma unroll
      for (int r = 0; r < 4; ++r)
        sums[r] += __shfl_xor(sums[r], m);
#pragma unroll
    for (int r = 0; r < 4; ++r) inv[r] = 1.f / sums[r];

    __syncthreads();   // all q/k LDS reads done before P overwrites the region

    // ---- P -> bf16 hi/lo in LDS (each wave writes its own 16 rows) ----
#pragma unroll
    for (int nj = 0; nj < 4; ++nj) {
      const int col = nj * 16 + l15;
#pragma unroll
      for (int r = 0; r < 4; ++r) {
        const int row = wid * 16 + l4 * 4 + r;
        float p = sv[nj][r] * inv[r];
        unsigned short hb = f2bf(p);
        ph_[row * 72 + col] = hb;
        pl_[row * 72 + col] = f2bf(p - bf2f(hb));
      }
    }

    // ---- PV (M=16/wave, N=32, K=64); A rows are own-wave P rows (in-wave LDS dep) ----
    {
      f32x4 oacc[2];
#pragma unroll
      for (int nc = 0; nc < 2; ++nc) oacc[nc] = (f32x4){0.f, 0.f, 0.f, 0.f};

#pragma unroll
      for (int ks = 0; ks < 2; ++ks) {
        const int kk = ks * 32 + l4 * 8;
        const int arow = wid * 16 + l15;
        bf16x8 Ap_h = *(const bf16x8*)(ph_ + arow * 72 + kk);
        bf16x8 Ap_l = *(const bf16x8*)(pl_ + arow * 72 + kk);
#pragma unroll
        for (int nc = 0; nc < 2; ++nc) {
          int bcol = nc * 16 + l15;
          bf16x8 Bv_h = *(const bf16x8*)(vth + bcol * 72 + kk);
          bf16x8 Bv_l = *(const bf16x8*)(vtl + bcol * 72 + kk);
          oacc[nc] = __builtin_amdgcn_mfma_f32_16x16x32_bf16(Ap_h, Bv_h, oacc[nc], 0, 0, 0);
          oacc[nc] = __builtin_amdgcn_mfma_f32_16x16x32_bf16(Ap_h, Bv_l, oacc[nc], 0, 0, 0);
          oacc[nc] = __builtin_amdgcn_mfma_f32_16x16x32_bf16(Ap_l, Bv_h, oacc[nc], 0, 0, 0);
        }
      }
#pragma unroll
      for (int nc = 0; nc < 2; ++nc) {
        int d = nc * 16 + l15;
#pragma unroll
        for (int r = 0; r < 4; ++r) {
          int row = wid * 16 + l4 * 4 + r;
          if (row < NTOK) {
            size_t idx = ((size_t)b * NTOK + row) * DIM + h * DH + d;
            float val = oacc[nc][r];
            if constexpr (sizeof(T) == 4) {
              unsigned short hb = f2bf(val);
              unsigned short lb = f2bf(val - bf2f(hb));
              ((unsigned int*)out)[idx] = ((unsigned int)hb << 16) | lb;
            } else {
              stf(out, idx, val);
            }
          }
        }
      }
    }
    __syncthreads();   // P/V reads done before next head's epilogue overwrites scratch
  }
}

// ---------- LDS-free MFMA in-place output projection ----------
// Block = 64 rows x 256 cols; 4 waves 2x2 (wave tile 32x128). B hi/lo read directly
// from L2-resident workspace panel; A from global (packed u32 fp32-path). One barrier
// before in-place stores (waves share A rows across the col split).
template <typename T>
__global__ __launch_bounds__(256, 4)
void proj_mfma_kernel(T* __restrict__ out, const unsigned short* __restrict__ wsb,
                      const T* __restrict__ proj_b, const int* __restrict__ flag, int want)
{
  if (*flag != want) return;
  constexpr int NS = (sizeof(T) == 4) ? 2 : 1;
  const int tid = threadIdx.x;
  const int lane = tid & 63, wid = tid >> 6;
  const int wrow = (wid & 1) * 32, wcol = (wid >> 1) * 128;
  const int l15 = lane & 15, l4 = lane >> 4;
  const size_t r0 = (size_t)blockIdx.x * 64;
  const unsigned short* ph = wsb + OFF_PH;
  const unsigned short* pl = wsb + OFF_PL;

  f32x4 acc[2][8];
#pragma unroll
  for (int fi = 0; fi < 2; ++fi)
#pragma unroll
    for (int ni = 0; ni < 8; ++ni) acc[fi][ni] = (f32x4){0.f, 0.f, 0.f, 0.f};

  for (int kt = 0; kt < DIM; kt += 32) {
    const int koff = kt + l4 * 8;
    bf16x8 Ah[2], Al[2];
#pragma unroll
    for (int fi = 0; fi < 2; ++fi) {
      size_t row = r0 + wrow + fi * 16 + l15;
      if constexpr (NS == 2) {
        const unsigned int* yp = reinterpret_cast<const unsigned int*>(out) + row * DIM + koff;
        uint4 u0 = *(const uint4*)yp;
        uint4 u1 = *(const uint4*)(yp + 4);
        unsigned int uu[8] = {u0.x, u0.y, u0.z, u0.w, u1.x, u1.y, u1.z, u1.w};
#pragma unroll
        for (int t = 0; t < 8; ++t) {
          Ah[fi][t] = (short)(uu[t] >> 16);
          Al[fi][t] = (short)(uu[t] & 0xFFFFu);
        }
      } else {
        Ah[fi] = *(const bf16x8*)(reinterpret_cast<const unsigned short*>(out) + row * DIM + koff);
      }
    }
#pragma unroll
    for (int ni = 0; ni < 8; ++ni) {
      const size_t boff = (size_t)(wcol + ni * 16 + l15) * DIM + koff;
      bf16x8 Bh = *(const bf16x8*)(ph + boff);
#pragma unroll
      for (int fi = 0; fi < 2; ++fi)
        acc[fi][ni] = __builtin_amdgcn_mfma_f32_16x16x32_bf16(Ah[fi], Bh, acc[fi][ni], 0, 0, 0);
      if constexpr (NS == 2) {
        bf16x8 Bl = *(const bf16x8*)(pl + boff);
#pragma unroll
        for (int fi = 0; fi < 2; ++fi) {
          acc[fi][ni] = __builtin_amdgcn_mfma_f32_16x16x32_bf16(Ah[fi], Bl, acc[fi][ni], 0, 0, 0);
          acc[fi][ni] = __builtin_amdgcn_mfma_f32_16x16x32_bf16(Al[fi], Bh, acc[fi][ni], 0, 0, 0);
        }
      }
    }
  }

  __syncthreads();   // all waves' A reads of these 64 rows done before in-place stores

#pragma unroll
  for (int fi = 0; fi < 2; ++fi) {
    size_t rbase = r0 + wrow + fi * 16 + l4 * 4;
#pragma unroll
    for (int ni = 0; ni < 8; ++ni) {
      int col = wcol + ni * 16 + l15;
      float bias = ldf(proj_b, (size_t)col);
#pragma unroll
      for (int r = 0; r < 4; ++r)
        stf(out, (rbase + r) * DIM + col, acc[fi][ni][r] + bias);
    }
  }
}

// ================= legacy fallback (ws too small for weight pre-split) =================
template <typename T>
__global__ __launch_bounds__(256, 2)
void win_attn_kernel(const T* __restrict__ x, const T* __restrict__ maskp,
                     const T* __restrict__ qkv_w, const T* __restrict__ qkv_b,
                     const T* __restrict__ rpb_table, const int* __restrict__ rel_index,
                     T* __restrict__ out, const int* __restrict__ flag, int want)
{
  if (*flag != want) return;

  const int b = blockIdx.x;
  const int h = blockIdx.y;
  const int tid = threadIdx.x;
  const int tx = tid & 15;
  const int ty = tid >> 4;

  __shared__ __align__(16) float xst[64][68];
  __shared__ __align__(16) float wt[96][68];
  __shared__ __align__(16) float qs[NTOK][36];
  __shared__ __align__(16) float ks2[NTOK][36];
  __shared__ __align__(16) float vs[NTOK][36];
  __shared__ __align__(16) float sm[NTOK][52];

  const float SCALE = 0.17677669529663687f;

  float acc[4][6];
#pragma unroll
  for (int i = 0; i < 4; ++i)
#pragma unroll
    for (int m = 0; m < 6; ++m) acc[i][m] = 0.0f;

  const size_t xbase = (size_t)b * NTOK * DIM;

  for (int kt = 0; kt < DIM; kt += 64) {
    for (int i = tid; i < NTOK * 64; i += 256) {
      int n = i >> 6, kk = i & 63;
      xst[n][kk] = ldf(x, xbase + (size_t)n * DIM + kt + kk);
    }
    for (int i = tid; i < 96 * 64; i += 256) {
      int j = i >> 6, kk = i & 63;
      int c = j >> 5, d = j & 31;
      wt[j][kk] = ldf(qkv_w, (size_t)(c * DIM + h * DH + d) * DIM + kt + kk);
    }
    __syncthreads();

#pragma unroll 2
    for (int kk = 0; kk < 64; kk += 4) {
      float4 av[4], bv[6];
#pragma unroll
      for (int i = 0; i < 4; ++i) av[i] = *(const float4*)&xst[ty + 16 * i][kk];
#pragma unroll
      for (int m = 0; m < 6; ++m) bv[m] = *(const float4*)&wt[tx + 16 * m][kk];
#pragma unroll
      for (int i = 0; i < 4; ++i)
#pragma unroll
        for (int m = 0; m < 6; ++m) {
          acc[i][m] += av[i].x * bv[m].x;
          acc[i][m] += av[i].y * bv[m].y;
          acc[i][m] += av[i].z * bv[m].z;
          acc[i][m] += av[i].w * bv[m].w;
        }
    }
    __syncthreads();
  }

#pragma unroll
  for (int i = 0; i < 4; ++i) {
    int n = ty + 16 * i;
    if (n < NTOK) {
#pragma unroll
      for (int m = 0; m < 6; ++m) {
        int j = tx + 16 * m;
        int c = j >> 5, d = j & 31;
        float v = acc[i][m] + ldf(qkv_b, c * DIM + h * DH + d);
        if (c == 0)      qs[n][d] = v * SCALE;
        else if (c == 1) ks2[n][d] = v;
        else             vs[n][d] = v;
      }
    }
  }
  __syncthreads();

  const int w = b & 63;
  for (int e = tid; e < NTOK * NTOK; e += 256) {
    int i = e / 49, j = e % 49;
    const float4* qi = (const float4*)qs[i];
    const float4* kj = (const float4*)ks2[j];
    float s = 0.0f;
#pragma unroll
    for (int d4 = 0; d4 < 8; ++d4) {
      float4 a = qi[d4], c = kj[d4];
      s += a.x * c.x + a.y * c.y + a.z * c.z + a.w * c.w;
    }
    s += ldf(rpb_table, (size_t)rel_index[e] * NH + h);
    s += ldf(maskp, (size_t)w * NTOK * NTOK + e);
    sm[i][j] = s;
  }
  __syncthreads();

  if (tid < NTOK) {
    int i = tid;
    float mx = -3.4e38f;
    for (int j = 0; j < NTOK; ++j) mx = fmaxf(mx, sm[i][j]);
    float sum = 0.0f;
    for (int j = 0; j < NTOK; ++j) {
      float ev = __expf(sm[i][j] - mx);
      sm[i][j] = ev;
      sum += ev;
    }
    float inv = 1.0f / sum;
    for (int j = 0; j < NTOK; ++j) sm[i][j] *= inv;
  }
  __syncthreads();

  for (int e = tid; e < NTOK * DH; e += 256) {
    int i = e >> 5, d = e & 31;
    float o = 0.0f;
    for (int j = 0; j < NTOK; ++j) o += sm[i][j] * vs[j][d];
    stf(out, ((size_t)b * NTOK + i) * DIM + h * DH + d, o);
  }
}

template <typename T>
__global__ __launch_bounds__(256, 2)
void proj_kernel(T* __restrict__ out, const T* __restrict__ proj_w,
                 const T* __restrict__ proj_b, const int* __restrict__ flag, int want)
{
  if (*flag != want) return;

  const int tid = threadIdx.x;
  const int tx = tid & 15;
  const int ty = tid >> 4;
  const size_t r0 = (size_t)blockIdx.x * 32;

  __shared__ __align__(16) float xs[32][260];
  __shared__ __align__(16) float pwt[256][36];

  for (int i = tid; i < 32 * 256; i += 256) {
    int n = i >> 8, c = i & 255;
    xs[n][c] = ldf((const T*)out, (r0 + n) * DIM + c);
  }
  __syncthreads();

  float acc[2][16];
#pragma unroll
  for (int i = 0; i < 2; ++i)
#pragma unroll
    for (int m = 0; m < 16; ++m) acc[i][m] = 0.0f;

  for (int kt = 0; kt < DIM; kt += 32) {
    for (int i = tid; i < 256 * 32; i += 256) {
      int j = i >> 5, kk = i & 31;
      pwt[j][kk] = ldf(proj_w, (size_t)j * DIM + kt + kk);
    }
    __syncthreads();

#pragma unroll 2
    for (int kk = 0; kk < 32; kk += 4) {
      float4 av[2], bv[16];
#pragma unroll
      for (int i = 0; i < 2; ++i) av[i] = *(const float4*)&xs[ty + 16 * i][kt + kk];
#pragma unroll
      for (int m = 0; m < 16; ++m) bv[m] = *(const float4*)&pwt[tx + 16 * m][kk];
#pragma unroll
      for (int i = 0; i < 2; ++i)
#pragma unroll
        for (int m = 0; m < 16; ++m) {
          acc[i][m] += av[i].x * bv[m].x;
          acc[i][m] += av[i].y * bv[m].y;
          acc[i][m] += av[i].z * bv[m].z;
          acc[i][m] += av[i].w * bv[m].w;
        }
    }
    __syncthreads();
  }

#pragma unroll
  for (int i = 0; i < 2; ++i) {
    int n = ty + 16 * i;
#pragma unroll
    for (int m = 0; m < 16; ++m) {
      int c = tx + 16 * m;
      stf(out, (r0 + n) * DIM + c, acc[i][m] + ldf(proj_b, c));
    }
  }
}

extern "C" void kernel_launch(void* const* d_in, const int* in_sizes, int n_in,
                              void* d_out, int out_size, void* d_ws, size_t ws_size,
                              hipStream_t stream) {
  const void* x      = d_in[0];
  const void* maskp  = d_in[1];
  const void* qkv_w  = d_in[2];
  const void* qkv_b  = d_in[3];
  const void* proj_w = d_in[4];
  const void* proj_b = d_in[5];
  const void* rpb    = d_in[6];
  const int*  rel    = (const int*)d_in[7];

  int* flag = (int*)d_ws;
  dtype_detect_kernel<<<dim3(1), dim3(64), 0, stream>>>((const unsigned int*)x, flag);

  const size_t WS_BASIC = 16 + 1048576;                       // flag + pre-split weights
  const size_t WS_FULL  = WS_BASIC + NH * NTOK * NTOK * 4;    // + rpb gather table
  if (ws_size >= WS_BASIC) {
    unsigned short* wsb = (unsigned short*)((char*)d_ws + 16);
    float* btbl = (float*)((char*)d_ws + WS_BASIC);
    const int has_bt = (ws_size >= WS_FULL) ? 1 : 0;
    const float* btp = has_bt ? btbl : nullptr;

    prep_w_kernel<float><<<dim3(256), dim3(256), 0, stream>>>(
        (const float*)qkv_w, (const float*)proj_w, (const float*)rpb, rel,
        wsb, btbl, has_bt, flag, 0);
    prep_w_kernel<__hip_bfloat16><<<dim3(256), dim3(256), 0, stream>>>(
        (const __hip_bfloat16*)qkv_w, (const __hip_bfloat16*)proj_w,
        (const __hip_bfloat16*)rpb, rel, wsb, btbl, has_bt, flag, 1);

    dim3 gA(NB, 4);   // 2 heads per block
    win_attn_mfma_kernel<float><<<gA, 256, 0, stream>>>(
        (const float*)x, (const float*)maskp, (const float*)qkv_b,
        (const float*)rpb, rel, wsb, btp, has_bt, (float*)d_out, flag, 0);
    win_attn_mfma_kernel<__hip_bfloat16><<<gA, 256, 0, stream>>>(
        (const __hip_bfloat16*)x, (const __hip_bfloat16*)maskp, (const __hip_bfloat16*)qkv_b,
        (const __hip_bfloat16*)rpb, rel, wsb, btp, has_bt, (__hip_bfloat16*)d_out, flag, 1);

    proj_mfma_kernel<float><<<dim3(1568), 256, 0, stream>>>(
        (float*)d_out, wsb, (const float*)proj_b, flag, 0);
    proj_mfma_kernel<__hip_bfloat16><<<dim3(1568), 256, 0, stream>>>(
        (__hip_bfloat16*)d_out, wsb, (const __hip_bfloat16*)proj_b, flag, 1);
  } else {
    dim3 gA(NB, NH);
    win_attn_kernel<float><<<gA, 256, 0, stream>>>(
        (const float*)x, (const float*)maskp, (const float*)qkv_w, (const float*)qkv_b,
        (const float*)rpb, rel, (float*)d_out, flag, 0);
    win_attn_kernel<__hip_bfloat16><<<gA, 256, 0, stream>>>(
        (const __hip_bfloat16*)x, (const __hip_bfloat16*)maskp, (const __hip_bfloat16*)qkv_w,
        (const __hip_bfloat16*)qkv_b, (const __hip_bfloat16*)rpb, rel,
        (__hip_bfloat16*)d_out, flag, 1);

    dim3 gB(3136);
    proj_kernel<float><<<gB, 256, 0, stream>>>(
        (float*)d_out, (const float*)proj_w, (const float*)proj_b, flag, 0);
    proj_kernel<__hip_bfloat16><<<gB, 256, 0, stream>>>(
        (__hip_bfloat16*)d_out, (const __hip_bfloat16*)proj_w, (const __hip_bfloat16*)proj_b,
        flag, 1);
  }
}

// Round 6
// 765.118 us; speedup vs baseline: 1.1779x; 1.1779x over previous
//
#include <hip/hip_runtime.h>
#include <hip/hip_bf16.h>

#define NTOK 49
#define DIM  256
#define NH   8
#define DH   32
#define NB   2048

// ---------- MFMA fragment types ----------
typedef __attribute__((ext_vector_type(8))) short bf16x8;
typedef __attribute__((ext_vector_type(4))) float f32x4;

// ---------- bf16 split helpers (native RNE cvt; split exact regardless of mode) ----------
__device__ __forceinline__ unsigned short f2bf(float f) {
  union { __hip_bfloat16 h; unsigned short u; } cv;
  cv.h = __float2bfloat16(f);
  return cv.u;
}
__device__ __forceinline__ float bf2f(unsigned short h) {
  return __uint_as_float(((unsigned int)h) << 16);
}

// ---------- dtype-polymorphic load/store ----------
__device__ __forceinline__ float ldf(const float* p, size_t i) { return p[i]; }
__device__ __forceinline__ float ldf(const __hip_bfloat16* p, size_t i) { return __bfloat162float(p[i]); }
__device__ __forceinline__ void stf(float* p, size_t i, float v) { p[i] = v; }
__device__ __forceinline__ void stf(__hip_bfloat16* p, size_t i, float v) { p[i] = __float2bfloat16(v); }

// ---------- dtype detector ----------
__global__ void dtype_detect_kernel(const unsigned int* __restrict__ x, int* flag) {
  if (blockIdx.x == 0 && threadIdx.x == 0) {
    int hits = 0;
    for (int i = 0; i < 64; ++i) {
      unsigned int lo = x[i] & 0xFFFFu;
      unsigned int e = (lo >> 7) & 0xFFu;
      if (e >= 110u && e <= 140u) hits++;
    }
    *flag = (hits >= 32) ? 1 : 0;   // 1 = bf16, 0 = fp32
  }
}

// ---------- workspace layout (ushorts, after 16-byte flag slot) ----------
#define OFF_QH 0
#define OFF_QL 196608
#define OFF_PH 393216
#define OFF_PL 458752
// bias table (f32, NH*2401) lives at byte offset 16 + 1048576 when ws allows

// ---------- prep: split weights into bf16 hi/lo; optional rpb-gather table ----------
template <typename T>
__global__ void prep_w_kernel(const T* __restrict__ qkv_w, const T* __restrict__ proj_w,
                              const T* __restrict__ rpb_table, const int* __restrict__ rel_index,
                              unsigned short* __restrict__ wsb, float* __restrict__ btbl,
                              int make_bt, const int* __restrict__ flag, int want) {
  if (*flag != want) return;
  int idx = blockIdx.x * blockDim.x + threadIdx.x;
  int stride = gridDim.x * blockDim.x;
  for (int i = idx; i < 768 * 256; i += stride) {
    float v = ldf(qkv_w, (size_t)i);
    unsigned short hb = f2bf(v);
    wsb[OFF_QH + i] = hb;
    wsb[OFF_QL + i] = f2bf(v - bf2f(hb));
  }
  for (int i = idx; i < 256 * 256; i += stride) {
    float v = ldf(proj_w, (size_t)i);
    unsigned short hb = f2bf(v);
    wsb[OFF_PH + i] = hb;
    wsb[OFF_PL + i] = f2bf(v - bf2f(hb));
  }
  if (make_bt) {
    for (int i = idx; i < NH * NTOK * NTOK; i += stride) {
      int h = i / (NTOK * NTOK), e = i - h * (NTOK * NTOK);
      btbl[i] = ldf(rpb_table, (size_t)rel_index[e] * NH + h);
    }
  }
}

// ---------- fully-MFMA fused QKV + window attention (2 heads / block) ----------
// Block = (window b, head-pair). 256 threads / 4 waves; wave pair (2hh,2hh+1) owns head hh.
// Phase 1: QKV GEMM  M=64(pad49) N=192(2 heads x 96) K=256, BK=64 shared x-staging;
//          B-frags (pre-split hi/lo) read directly from global/L2.  acc[4][3]=48 VGPR.
// Per head hh: pair-parallel epilogue -> QK^T (wave=16 rows x 64 cols, K=32) with
//          IN-REGISTER softmax (shfl_xor over 16-lane groups) -> P bf16 hi/lo to LDS -> PV.
// LDS 29696B: q/k hi/lo [64][40]us (20480) | V^T hi/lo [32][72]us (9216);
//          P hi/lo [64][72]us (18432) aliases q/k after post-QK^T barrier.
// launch_bounds(256,3): 170 VGPR/wave budget -> NO SPILL (the (256,4) 128-cap spilled:
// round-5 PMC showed +620MB scratch writes, VGPR_Count 64). 3 blocks/CU, 12 waves/CU.
template <typename T>
__global__ __launch_bounds__(256, 3)
void win_attn_mfma_kernel(const T* __restrict__ x, const T* __restrict__ maskp,
                          const T* __restrict__ qkv_b,
                          const T* __restrict__ rpb_table, const int* __restrict__ rel_index,
                          const unsigned short* __restrict__ wsb,
                          const float* __restrict__ btbl, int has_bt,
                          T* __restrict__ out, const int* __restrict__ flag, int want)
{
  if (*flag != want) return;
  constexpr int NS = (sizeof(T) == 4) ? 2 : 1;
  __shared__ __align__(16) char smem[29696];

  // staging views (dead after phase 1)
  unsigned short* xh = (unsigned short*)smem;           // [64][72]
  unsigned short* xl = xh + 64 * 72;                    // (NS==2), ends @18432B
  // attention views
  unsigned short* qh_ = (unsigned short*)smem;          // [64][40] q hi (pre-scaled)
  unsigned short* ql_ = qh_ + 64 * 40;
  unsigned short* kh_ = ql_ + 64 * 40;
  unsigned short* kl_ = kh_ + 64 * 40;                  // ends @20480B
  unsigned short* vth = kl_ + 64 * 40;                  // [32][72] V^T hi (row=d, col=token)
  unsigned short* vtl = vth + 32 * 72;                  // ends @29696B
  unsigned short* ph_ = (unsigned short*)smem;          // [64][72] P hi (aliases q/k)
  unsigned short* pl_ = ph_ + 64 * 72;                  // ends @18432B

  const int b = blockIdx.x;
  const int hbase = blockIdx.y * 2;
  const int tid = threadIdx.x;
  const int lane = tid & 63, wid = tid >> 6;
  const int l15 = lane & 15, l4 = lane >> 4;
  const int myh = hbase + (wid >> 1);                   // this wave's head
  const int ncol0 = (wid & 1) * 48;                     // col-slice within head's 96
  const float SCALE = 0.17677669529663687f;             // 32^-0.5
  const size_t xbase = (size_t)b * NTOK * DIM;
  const unsigned short* qwh = wsb + OFF_QH;

  // B row bases (hi array; lo at +OFF_QL)
  size_t brow[3];
#pragma unroll
  for (int ni = 0; ni < 3; ++ni) {
    int j = ncol0 + ni * 16 + l15;
    brow[ni] = (size_t)((j >> 5) * DIM + myh * DH + (j & 31)) * DIM;
  }

  // zero V^T pad tokens j=49..63 ONCE (region disjoint from staging; epilogue writes j<49)
  for (int i = tid; i < 32 * 15; i += 256) {
    int d = i / 15, j2 = 49 + i % 15;
    vth[d * 72 + j2] = 0;
    vtl[d * 72 + j2] = 0;
  }

  // ================= Phase 1: QKV GEMM =================
  f32x4 acc[4][3];
#pragma unroll
  for (int mi = 0; mi < 4; ++mi)
#pragma unroll
    for (int ni = 0; ni < 3; ++ni) acc[mi][ni] = (f32x4){0.f, 0.f, 0.f, 0.f};

  for (int kt = 0; kt < DIM; kt += 64) {
    if constexpr (NS == 2) {
      const float* xf = reinterpret_cast<const float*>(x);
      for (int i = tid; i < NTOK * 16; i += 256) {
        int n = i >> 4, k4 = (i & 15) * 4;
        const float4 v = *(const float4*)(xf + xbase + n * DIM + kt + k4);
        ushort4 hh, ll;
        hh.x = f2bf(v.x); ll.x = f2bf(v.x - bf2f(hh.x));
        hh.y = f2bf(v.y); ll.y = f2bf(v.y - bf2f(hh.y));
        hh.z = f2bf(v.z); ll.z = f2bf(v.z - bf2f(hh.z));
        hh.w = f2bf(v.w); ll.w = f2bf(v.w - bf2f(hh.w));
        *(ushort4*)(xh + n * 72 + k4) = hh;
        *(ushort4*)(xl + n * 72 + k4) = ll;
      }
    } else {
      const unsigned short* xu = reinterpret_cast<const unsigned short*>(x);
      for (int i = tid; i < NTOK * 8; i += 256) {
        int n = i >> 3, k8 = (i & 7) * 8;
        *(int4*)(xh + n * 72 + k8) = *(const int4*)(xu + xbase + n * DIM + kt + k8);
      }
    }
    __syncthreads();

#pragma unroll
    for (int ks = 0; ks < 2; ++ks) {
      const int ka = ks * 32 + l4 * 8;
      bf16x8 Ah[4], Al[4];
#pragma unroll
      for (int mi = 0; mi < 4; ++mi) {
        int off = (mi * 16 + l15) * 72 + ka;
        Ah[mi] = *(const bf16x8*)(xh + off);
        if constexpr (NS == 2) Al[mi] = *(const bf16x8*)(xl + off);
      }
#pragma unroll
      for (int ni = 0; ni < 3; ++ni) {
        const unsigned short* bp = qwh + brow[ni] + kt + ka;
        bf16x8 Bh = *(const bf16x8*)bp;
#pragma unroll
        for (int mi = 0; mi < 4; ++mi)
          acc[mi][ni] = __builtin_amdgcn_mfma_f32_16x16x32_bf16(Ah[mi], Bh, acc[mi][ni], 0, 0, 0);
        if constexpr (NS == 2) {
          bf16x8 Bl = *(const bf16x8*)(bp + OFF_QL);
#pragma unroll
          for (int mi = 0; mi < 4; ++mi) {
            acc[mi][ni] = __builtin_amdgcn_mfma_f32_16x16x32_bf16(Ah[mi], Bl, acc[mi][ni], 0, 0, 0);
            acc[mi][ni] = __builtin_amdgcn_mfma_f32_16x16x32_bf16(Al[mi], Bh, acc[mi][ni], 0, 0, 0);
          }
        }
      }
    }
    __syncthreads();   // staging reads done before restage / scratch aliasing
  }

  // ================= per-head attention loop (2 heads) =================
  const size_t mbase = (size_t)(b & 63) * (NTOK * NTOK);
  for (int hh = 0; hh < 2; ++hh) {
    const int h = hbase + hh;

    // ---- epilogue: wave pair (2hh, 2hh+1) writes q/k/v for head hh ----
    if ((wid >> 1) == hh) {
#pragma unroll
      for (int mi = 0; mi < 4; ++mi) {
        int rbase = mi * 16 + l4 * 4;
#pragma unroll
        for (int ni = 0; ni < 3; ++ni) {
          int j = ncol0 + ni * 16 + l15;
          int c = j >> 5, d = j & 31;
          float bias = ldf(qkv_b, (size_t)(c * DIM + h * DH + d));
#pragma unroll
          for (int r = 0; r < 4; ++r) {
            int row = rbase + r;
            if (row < NTOK) {
              float val = acc[mi][ni][r] + bias;
              if (c == 0) {
                val *= SCALE;
                unsigned short hb = f2bf(val);
                qh_[row * 40 + d] = hb;
                ql_[row * 40 + d] = f2bf(val - bf2f(hb));
              } else if (c == 1) {
                unsigned short hb = f2bf(val);
                kh_[row * 40 + d] = hb;
                kl_[row * 40 + d] = f2bf(val - bf2f(hb));
              } else {
                unsigned short hb = f2bf(val);
                vth[d * 72 + row] = hb;
                vtl[d * 72 + row] = f2bf(val - bf2f(hb));
              }
            }
          }
        }
      }
    }
    __syncthreads();

    // ---- QK^T: wave owns rows wid*16..+15, cols 0..63 (K=32) ----
    f32x4 sacc[4];
#pragma unroll
    for (int nj = 0; nj < 4; ++nj) sacc[nj] = (f32x4){0.f, 0.f, 0.f, 0.f};
    {
      const int qoff = (wid * 16 + l15) * 40 + l4 * 8;
      bf16x8 Aqh = *(const bf16x8*)(qh_ + qoff);
      bf16x8 Aql = *(const bf16x8*)(ql_ + qoff);
#pragma unroll
      for (int nj = 0; nj < 4; ++nj) {
        const int koff2 = (nj * 16 + l15) * 40 + l4 * 8;
        bf16x8 Bkh = *(const bf16x8*)(kh_ + koff2);
        bf16x8 Bkl = *(const bf16x8*)(kl_ + koff2);
        sacc[nj] = __builtin_amdgcn_mfma_f32_16x16x32_bf16(Aqh, Bkh, sacc[nj], 0, 0, 0);
        sacc[nj] = __builtin_amdgcn_mfma_f32_16x16x32_bf16(Aqh, Bkl, sacc[nj], 0, 0, 0);
        sacc[nj] = __builtin_amdgcn_mfma_f32_16x16x32_bf16(Aql, Bkh, sacc[nj], 0, 0, 0);
      }
    }

    // ---- bias + mask + IN-REGISTER softmax ----
    // lane holds rows {wid*16+l4*4+r} x cols {nj*16+l15}; row-reduce = fold nj + shfl_xor(1,2,4,8)
    float sv[4][4];
#pragma unroll
    for (int nj = 0; nj < 4; ++nj) {
      const int col = nj * 16 + l15;
#pragma unroll
      for (int r = 0; r < 4; ++r) {
        const int row = wid * 16 + l4 * 4 + r;
        float s = -3.4e38f;
        if (col < NTOK && row < NTOK) {
          const int e = row * NTOK + col;
          float bias = has_bt ? btbl[h * (NTOK * NTOK) + e]
                              : ldf(rpb_table, (size_t)rel_index[e] * NH + h);
          s = sacc[nj][r] + bias + ldf(maskp, mbase + e);
        }
        sv[nj][r] = s;
      }
    }
    float mx[4], sums[4], inv[4];
#pragma unroll
    for (int r = 0; r < 4; ++r)
      mx[r] = fmaxf(fmaxf(sv[0][r], sv[1][r]), fmaxf(sv[2][r], sv[3][r]));
#pragma unroll
    for (int m = 1; m <= 8; m <<= 1)
#pragma unroll
      for (int r = 0; r < 4; ++r)
        mx[r] = fmaxf(mx[r], __shfl_xor(mx[r], m));
#pragma unroll
    for (int r = 0; r < 4; ++r) sums[r] = 0.f;
#pragma unroll
    for (int nj = 0; nj < 4; ++nj) {
      const int col = nj * 16 + l15;
#pragma unroll
      for (int r = 0; r < 4; ++r) {
        float ev = (col < NTOK) ? __expf(sv[nj][r] - mx[r]) : 0.f;
        sv[nj][r] = ev;
        sums[r] += ev;
      }
    }
#pragma unroll
    for (int m = 1; m <= 8; m <<= 1)
#pragma unroll
      for (int r = 0; r < 4; ++r)
        sums[r] += __shfl_xor(sums[r], m);
#pragma unroll
    for (int r = 0; r < 4; ++r) inv[r] = 1.f / sums[r];

    __syncthreads();   // all q/k LDS reads done before P overwrites the region

    // ---- P -> bf16 hi/lo in LDS (each wave writes its own 16 rows) ----
#pragma unroll
    for (int nj = 0; nj < 4; ++nj) {
      const int col = nj * 16 + l15;
#pragma unroll
      for (int r = 0; r < 4; ++r) {
        const int row = wid * 16 + l4 * 4 + r;
        float p = sv[nj][r] * inv[r];
        unsigned short hb = f2bf(p);
        ph_[row * 72 + col] = hb;
        pl_[row * 72 + col] = f2bf(p - bf2f(hb));
      }
    }

    // ---- PV (M=16/wave, N=32, K=64); A rows are own-wave P rows (in-wave LDS dep) ----
    {
      f32x4 oacc[2];
#pragma unroll
      for (int nc = 0; nc < 2; ++nc) oacc[nc] = (f32x4){0.f, 0.f, 0.f, 0.f};

#pragma unroll
      for (int ks = 0; ks < 2; ++ks) {
        const int kk = ks * 32 + l4 * 8;
        const int arow = wid * 16 + l15;
        bf16x8 Ap_h = *(const bf16x8*)(ph_ + arow * 72 + kk);
        bf16x8 Ap_l = *(const bf16x8*)(pl_ + arow * 72 + kk);
#pragma unroll
        for (int nc = 0; nc < 2; ++nc) {
          int bcol = nc * 16 + l15;
          bf16x8 Bv_h = *(const bf16x8*)(vth + bcol * 72 + kk);
          bf16x8 Bv_l = *(const bf16x8*)(vtl + bcol * 72 + kk);
          oacc[nc] = __builtin_amdgcn_mfma_f32_16x16x32_bf16(Ap_h, Bv_h, oacc[nc], 0, 0, 0);
          oacc[nc] = __builtin_amdgcn_mfma_f32_16x16x32_bf16(Ap_h, Bv_l, oacc[nc], 0, 0, 0);
          oacc[nc] = __builtin_amdgcn_mfma_f32_16x16x32_bf16(Ap_l, Bv_h, oacc[nc], 0, 0, 0);
        }
      }
#pragma unroll
      for (int nc = 0; nc < 2; ++nc) {
        int d = nc * 16 + l15;
#pragma unroll
        for (int r = 0; r < 4; ++r) {
          int row = wid * 16 + l4 * 4 + r;
          if (row < NTOK) {
            size_t idx = ((size_t)b * NTOK + row) * DIM + h * DH + d;
            float val = oacc[nc][r];
            if constexpr (sizeof(T) == 4) {
              unsigned short hb = f2bf(val);
              unsigned short lb = f2bf(val - bf2f(hb));
              ((unsigned int*)out)[idx] = ((unsigned int)hb << 16) | lb;
            } else {
              stf(out, idx, val);
            }
          }
        }
      }
    }
    __syncthreads();   // P/V reads done before next head's epilogue overwrites scratch
  }
}

// ---------- LDS-free MFMA in-place output projection ----------
// Block = 64 rows x 256 cols; 4 waves 2x2 (wave tile 32x128). B hi/lo read directly
// from L2-resident workspace panel; A from global (packed u32 fp32-path). One barrier
// before in-place stores. launch_bounds(256,3): 170 VGPR budget (acc=64 + unpack temps
// overflowed the (256,4) 128-cap -> spills).
template <typename T>
__global__ __launch_bounds__(256, 3)
void proj_mfma_kernel(T* __restrict__ out, const unsigned short* __restrict__ wsb,
                      const T* __restrict__ proj_b, const int* __restrict__ flag, int want)
{
  if (*flag != want) return;
  constexpr int NS = (sizeof(T) == 4) ? 2 : 1;
  const int tid = threadIdx.x;
  const int lane = tid & 63, wid = tid >> 6;
  const int wrow = (wid & 1) * 32, wcol = (wid >> 1) * 128;
  const int l15 = lane & 15, l4 = lane >> 4;
  const size_t r0 = (size_t)blockIdx.x * 64;
  const unsigned short* ph = wsb + OFF_PH;
  const unsigned short* pl = wsb + OFF_PL;

  f32x4 acc[2][8];
#pragma unroll
  for (int fi = 0; fi < 2; ++fi)
#pragma unroll
    for (int ni = 0; ni < 8; ++ni) acc[fi][ni] = (f32x4){0.f, 0.f, 0.f, 0.f};

  for (int kt = 0; kt < DIM; kt += 32) {
    const int koff = kt + l4 * 8;
    bf16x8 Ah[2], Al[2];
#pragma unroll
    for (int fi = 0; fi < 2; ++fi) {
      size_t row = r0 + wrow + fi * 16 + l15;
      if constexpr (NS == 2) {
        const unsigned int* yp = reinterpret_cast<const unsigned int*>(out) + row * DIM + koff;
        uint4 u0 = *(const uint4*)yp;
        uint4 u1 = *(const uint4*)(yp + 4);
        unsigned int uu[8] = {u0.x, u0.y, u0.z, u0.w, u1.x, u1.y, u1.z, u1.w};
#pragma unroll
        for (int t = 0; t < 8; ++t) {
          Ah[fi][t] = (short)(uu[t] >> 16);
          Al[fi][t] = (short)(uu[t] & 0xFFFFu);
        }
      } else {
        Ah[fi] = *(const bf16x8*)(reinterpret_cast<const unsigned short*>(out) + row * DIM + koff);
      }
    }
#pragma unroll
    for (int ni = 0; ni < 8; ++ni) {
      const size_t boff = (size_t)(wcol + ni * 16 + l15) * DIM + koff;
      bf16x8 Bh = *(const bf16x8*)(ph + boff);
#pragma unroll
      for (int fi = 0; fi < 2; ++fi)
        acc[fi][ni] = __builtin_amdgcn_mfma_f32_16x16x32_bf16(Ah[fi], Bh, acc[fi][ni], 0, 0, 0);
      if constexpr (NS == 2) {
        bf16x8 Bl = *(const bf16x8*)(pl + boff);
#pragma unroll
        for (int fi = 0; fi < 2; ++fi) {
          acc[fi][ni] = __builtin_amdgcn_mfma_f32_16x16x32_bf16(Ah[fi], Bl, acc[fi][ni], 0, 0, 0);
          acc[fi][ni] = __builtin_amdgcn_mfma_f32_16x16x32_bf16(Al[fi], Bh, acc[fi][ni], 0, 0, 0);
        }
      }
    }
  }

  __syncthreads();   // all waves' A reads of these 64 rows done before in-place stores

#pragma unroll
  for (int fi = 0; fi < 2; ++fi) {
    size_t rbase = r0 + wrow + fi * 16 + l4 * 4;
#pragma unroll
    for (int ni = 0; ni < 8; ++ni) {
      int col = wcol + ni * 16 + l15;
      float bias = ldf(proj_b, (size_t)col);
#pragma unroll
      for (int r = 0; r < 4; ++r)
        stf(out, (rbase + r) * DIM + col, acc[fi][ni][r] + bias);
    }
  }
}

// ================= legacy fallback (ws too small for weight pre-split) =================
template <typename T>
__global__ __launch_bounds__(256, 2)
void win_attn_kernel(const T* __restrict__ x, const T* __restrict__ maskp,
                     const T* __restrict__ qkv_w, const T* __restrict__ qkv_b,
                     const T* __restrict__ rpb_table, const int* __restrict__ rel_index,
                     T* __restrict__ out, const int* __restrict__ flag, int want)
{
  if (*flag != want) return;

  const int b = blockIdx.x;
  const int h = blockIdx.y;
  const int tid = threadIdx.x;
  const int tx = tid & 15;
  const int ty = tid >> 4;

  __shared__ __align__(16) float xst[64][68];
  __shared__ __align__(16) float wt[96][68];
  __shared__ __align__(16) float qs[NTOK][36];
  __shared__ __align__(16) float ks2[NTOK][36];
  __shared__ __align__(16) float vs[NTOK][36];
  __shared__ __align__(16) float sm[NTOK][52];

  const float SCALE = 0.17677669529663687f;

  float acc[4][6];
#pragma unroll
  for (int i = 0; i < 4; ++i)
#pragma unroll
    for (int m = 0; m < 6; ++m) acc[i][m] = 0.0f;

  const size_t xbase = (size_t)b * NTOK * DIM;

  for (int kt = 0; kt < DIM; kt += 64) {
    for (int i = tid; i < NTOK * 64; i += 256) {
      int n = i >> 6, kk = i & 63;
      xst[n][kk] = ldf(x, xbase + (size_t)n * DIM + kt + kk);
    }
    for (int i = tid; i < 96 * 64; i += 256) {
      int j = i >> 6, kk = i & 63;
      int c = j >> 5, d = j & 31;
      wt[j][kk] = ldf(qkv_w, (size_t)(c * DIM + h * DH + d) * DIM + kt + kk);
    }
    __syncthreads();

#pragma unroll 2
    for (int kk = 0; kk < 64; kk += 4) {
      float4 av[4], bv[6];
#pragma unroll
      for (int i = 0; i < 4; ++i) av[i] = *(const float4*)&xst[ty + 16 * i][kk];
#pragma unroll
      for (int m = 0; m < 6; ++m) bv[m] = *(const float4*)&wt[tx + 16 * m][kk];
#pragma unroll
      for (int i = 0; i < 4; ++i)
#pragma unroll
        for (int m = 0; m < 6; ++m) {
          acc[i][m] += av[i].x * bv[m].x;
          acc[i][m] += av[i].y * bv[m].y;
          acc[i][m] += av[i].z * bv[m].z;
          acc[i][m] += av[i].w * bv[m].w;
        }
    }
    __syncthreads();
  }

#pragma unroll
  for (int i = 0; i < 4; ++i) {
    int n = ty + 16 * i;
    if (n < NTOK) {
#pragma unroll
      for (int m = 0; m < 6; ++m) {
        int j = tx + 16 * m;
        int c = j >> 5, d = j & 31;
        float v = acc[i][m] + ldf(qkv_b, c * DIM + h * DH + d);
        if (c == 0)      qs[n][d] = v * SCALE;
        else if (c == 1) ks2[n][d] = v;
        else             vs[n][d] = v;
      }
    }
  }
  __syncthreads();

  const int w = b & 63;
  for (int e = tid; e < NTOK * NTOK; e += 256) {
    int i = e / 49, j = e % 49;
    const float4* qi = (const float4*)qs[i];
    const float4* kj = (const float4*)ks2[j];
    float s = 0.0f;
#pragma unroll
    for (int d4 = 0; d4 < 8; ++d4) {
      float4 a = qi[d4], c = kj[d4];
      s += a.x * c.x + a.y * c.y + a.z * c.z + a.w * c.w;
    }
    s += ldf(rpb_table, (size_t)rel_index[e] * NH + h);
    s += ldf(maskp, (size_t)w * NTOK * NTOK + e);
    sm[i][j] = s;
  }
  __syncthreads();

  if (tid < NTOK) {
    int i = tid;
    float mx = -3.4e38f;
    for (int j = 0; j < NTOK; ++j) mx = fmaxf(mx, sm[i][j]);
    float sum = 0.0f;
    for (int j = 0; j < NTOK; ++j) {
      float ev = __expf(sm[i][j] - mx);
      sm[i][j] = ev;
      sum += ev;
    }
    float inv = 1.0f / sum;
    for (int j = 0; j < NTOK; ++j) sm[i][j] *= inv;
  }
  __syncthreads();

  for (int e = tid; e < NTOK * DH; e += 256) {
    int i = e >> 5, d = e & 31;
    float o = 0.0f;
    for (int j = 0; j < NTOK; ++j) o += sm[i][j] * vs[j][d];
    stf(out, ((size_t)b * NTOK + i) * DIM + h * DH + d, o);
  }
}

template <typename T>
__global__ __launch_bounds__(256, 2)
void proj_kernel(T* __restrict__ out, const T* __restrict__ proj_w,
                 const T* __restrict__ proj_b, const int* __restrict__ flag, int want)
{
  if (*flag != want) return;

  const int tid = threadIdx.x;
  const int tx = tid & 15;
  const int ty = tid >> 4;
  const size_t r0 = (size_t)blockIdx.x * 32;

  __shared__ __align__(16) float xs[32][260];
  __shared__ __align__(16) float pwt[256][36];

  for (int i = tid; i < 32 * 256; i += 256) {
    int n = i >> 8, c = i & 255;
    xs[n][c] = ldf((const T*)out, (r0 + n) * DIM + c);
  }
  __syncthreads();

  float acc[2][16];
#pragma unroll
  for (int i = 0; i < 2; ++i)
#pragma unroll
    for (int m = 0; m < 16; ++m) acc[i][m] = 0.0f;

  for (int kt = 0; kt < DIM; kt += 32) {
    for (int i = tid; i < 256 * 32; i += 256) {
      int j = i >> 5, kk = i & 31;
      pwt[j][kk] = ldf(proj_w, (size_t)j * DIM + kt + kk);
    }
    __syncthreads();

#pragma unroll 2
    for (int kk = 0; kk < 32; kk += 4) {
      float4 av[2], bv[16];
#pragma unroll
      for (int i = 0; i < 2; ++i) av[i] = *(const float4*)&xs[ty + 16 * i][kt + kk];
#pragma unroll
      for (int m = 0; m < 16; ++m) bv[m] = *(const float4*)&pwt[tx + 16 * m][kk];
#pragma unroll
      for (int i = 0; i < 2; ++i)
#pragma unroll
        for (int m = 0; m < 16; ++m) {
          acc[i][m] += av[i].x * bv[m].x;
          acc[i][m] += av[i].y * bv[m].y;
          acc[i][m] += av[i].z * bv[m].z;
          acc[i][m] += av[i].w * bv[m].w;
        }
    }
    __syncthreads();
  }

#pragma unroll
  for (int i = 0; i < 2; ++i) {
    int n = ty + 16 * i;
#pragma unroll
    for (int m = 0; m < 16; ++m) {
      int c = tx + 16 * m;
      stf(out, (r0 + n) * DIM + c, acc[i][m] + ldf(proj_b, c));
    }
  }
}

extern "C" void kernel_launch(void* const* d_in, const int* in_sizes, int n_in,
                              void* d_out, int out_size, void* d_ws, size_t ws_size,
                              hipStream_t stream) {
  const void* x      = d_in[0];
  const void* maskp  = d_in[1];
  const void* qkv_w  = d_in[2];
  const void* qkv_b  = d_in[3];
  const void* proj_w = d_in[4];
  const void* proj_b = d_in[5];
  const void* rpb    = d_in[6];
  const int*  rel    = (const int*)d_in[7];

  int* flag = (int*)d_ws;
  dtype_detect_kernel<<<dim3(1), dim3(64), 0, stream>>>((const unsigned int*)x, flag);

  const size_t WS_BASIC = 16 + 1048576;                       // flag + pre-split weights
  const size_t WS_FULL  = WS_BASIC + NH * NTOK * NTOK * 4;    // + rpb gather table
  if (ws_size >= WS_BASIC) {
    unsigned short* wsb = (unsigned short*)((char*)d_ws + 16);
    float* btbl = (float*)((char*)d_ws + WS_BASIC);
    const int has_bt = (ws_size >= WS_FULL) ? 1 : 0;
    const float* btp = has_bt ? btbl : nullptr;

    prep_w_kernel<float><<<dim3(256), dim3(256), 0, stream>>>(
        (const float*)qkv_w, (const float*)proj_w, (const float*)rpb, rel,
        wsb, btbl, has_bt, flag, 0);
    prep_w_kernel<__hip_bfloat16><<<dim3(256), dim3(256), 0, stream>>>(
        (const __hip_bfloat16*)qkv_w, (const __hip_bfloat16*)proj_w,
        (const __hip_bfloat16*)rpb, rel, wsb, btbl, has_bt, flag, 1);

    dim3 gA(NB, 4);   // 2 heads per block
    win_attn_mfma_kernel<float><<<gA, 256, 0, stream>>>(
        (const float*)x, (const float*)maskp, (const float*)qkv_b,
        (const float*)rpb, rel, wsb, btp, has_bt, (float*)d_out, flag, 0);
    win_attn_mfma_kernel<__hip_bfloat16><<<gA, 256, 0, stream>>>(
        (const __hip_bfloat16*)x, (const __hip_bfloat16*)maskp, (const __hip_bfloat16*)qkv_b,
        (const __hip_bfloat16*)rpb, rel, wsb, btp, has_bt, (__hip_bfloat16*)d_out, flag, 1);

    proj_mfma_kernel<float><<<dim3(1568), 256, 0, stream>>>(
        (float*)d_out, wsb, (const float*)proj_b, flag, 0);
    proj_mfma_kernel<__hip_bfloat16><<<dim3(1568), 256, 0, stream>>>(
        (__hip_bfloat16*)d_out, wsb, (const __hip_bfloat16*)proj_b, flag, 1);
  } else {
    dim3 gA(NB, NH);
    win_attn_kernel<float><<<gA, 256, 0, stream>>>(
        (const float*)x, (const float*)maskp, (const float*)qkv_w, (const float*)qkv_b,
        (const float*)rpb, rel, (float*)d_out, flag, 0);
    win_attn_kernel<__hip_bfloat16><<<gA, 256, 0, stream>>>(
        (const __hip_bfloat16*)x, (const __hip_bfloat16*)maskp, (const __hip_bfloat16*)qkv_w,
        (const __hip_bfloat16*)qkv_b, (const __hip_bfloat16*)rpb, rel,
        (__hip_bfloat16*)d_out, flag, 1);

    dim3 gB(3136);
    proj_kernel<float><<<gB, 256, 0, stream>>>(
        (float*)d_out, (const float*)proj_w, (const float*)proj_b, flag, 0);
    proj_kernel<__hip_bfloat16><<<gB, 256, 0, stream>>>(
        (__hip_bfloat16*)d_out, (const __hip_bfloat16*)proj_w, (const __hip_bfloat16*)proj_b,
        flag, 1);
  }
}